// Round 8
// baseline (634.482 us; speedup 1.0000x reference)
//
#include <hip/hip_runtime.h>

#define HH 256
#define WW 384
#define HWSZ (HH*WW)
#define NL 3
#define ANGN 7
#define A2N 49
#define NBATCH 2
#define RANKN 4
#define CN 3
#define RCN (RANKN*CN)

#define WPX 4                       // pixels per thread
#define GX (WW/WPX)                 // 96 pixel-groups per row
#define PBN ((HH*GX)/256)           // 96 pixel-blocks per (n,k,c)
// grid = NBATCH*CN*ANGN*PBN = 2*3*7*96 = 4032 = 8*504 (XCD-bijective)

// NOTE (round-2 post-mortem): every register-array subscript must be a
// compile-time literal — runtime-indexed locals go to scratch (2.5 GB spill,
// 1137 us). All j/l loops are macro-instantiated with literal indices.
// NOTE (round-5 post-mortem): no explicit software pipeline — VGPR 176 cut
// occupancy to 10.7% and regressed 92->139 us. TLP > ILP for this kernel.
// NOTE (round-7 post-mortem): every variant with VGPR in (64,128] sits in the
// 4-waves/SIMD occupancy bucket and is latency-bound (~90-147 us, VALUBusy
// ~30%). Round-0 at VGPR=64 got 8 waves/SIMD, 73% VALUBusy. Hence the
// __launch_bounds__(256, 8) below: cap VGPR at 512/8 = 64.

// lerp over staged window h[2..9]; sample px t of view j uses h[K+t], h[K+t+1]
#define LERP1(HL, I, WX) ((HL)[I] + (WX) * ((HL)[(I)+1] - (HL)[I]))
#define PROD_SET(P, HL, K, WX) do {                           \
    P[0] = LERP1(HL, (K)+0, WX); P[1] = LERP1(HL, (K)+1, WX); \
    P[2] = LERP1(HL, (K)+2, WX); P[3] = LERP1(HL, (K)+3, WX); \
} while (0)
#define PROD_MUL(P, HL, K, WX) do {                           \
    P[0] *= LERP1(HL, (K)+0, WX); P[1] *= LERP1(HL, (K)+1, WX); \
    P[2] *= LERP1(HL, (K)+2, WX); P[3] *= LERP1(HL, (K)+3, WX); \
} while (0)
#define ACC_FMA(A, P, HL, K, WX) do {                         \
    A[0] = fmaf(P[0], LERP1(HL, (K)+0, WX), A[0]);            \
    A[1] = fmaf(P[1], LERP1(HL, (K)+1, WX), A[1]);            \
    A[2] = fmaf(P[2], LERP1(HL, (K)+2, WX), A[2]);            \
    A[3] = fmaf(P[3], LERP1(HL, (K)+3, WX), A[3]);            \
} while (0)

// stage one (layer L, rank r) row-pair directly from UNPADDED input.
// Quads at cols xb-4 (clamped), xb, xb+4 (clamped); border replicate via 4
// selects on the vertical-lerp results. h[i] = value at col xb-4+i, i in 2..9.
#define STAGE(HL, L) do {                                                   \
    const float* cb = low_rank + (size_t)(((n * NL + (L)) * RANKN + r) * CN + c) * HWSZ; \
    const float* p0 = cb + off##L;                                          \
    const float* p1 = p0 + WW;                                              \
    float4 a0 = *(const float4*)(p0 + dq0);                                 \
    float4 a1 = *(const float4*)(p0);                                       \
    float4 a2 = *(const float4*)(p0 + dq2);                                 \
    float4 b0 = *(const float4*)(p1 + dq0);                                 \
    float4 b1 = *(const float4*)(p1);                                       \
    float4 b2 = *(const float4*)(p1 + dq2);                                 \
    float w = wy##L;                                                        \
    float v0x = a0.x + w * (b0.x - a0.x);                                   \
    float v0z = a0.z + w * (b0.z - a0.z);                                   \
    float v0w = a0.w + w * (b0.w - a0.w);                                   \
    HL[2] = eL ? v0x : v0z;                                                 \
    HL[3] = eL ? v0x : v0w;                                                 \
    HL[4] = a1.x + w * (b1.x - a1.x);                                       \
    HL[5] = a1.y + w * (b1.y - a1.y);                                       \
    HL[6] = a1.z + w * (b1.z - a1.z);                                       \
    HL[7] = a1.w + w * (b1.w - a1.w);                                       \
    float v2x = a2.x + w * (b2.x - a2.x);                                   \
    float v2y = a2.y + w * (b2.y - a2.y);                                   \
    float v2w = a2.w + w * (b2.w - a2.w);                                   \
    HL[8] = eR ? v2w : v2x;                                                 \
    HL[9] = eR ? v2w : v2y;                                                 \
} while (0)

#define SWITCH_SET(P, HL, LI, J) do {                                      \
    float wx = wx_##LI##_##J;                                              \
    switch (i0_##LI##_##J) {                                               \
        case 2:  PROD_SET(P, HL, 2, wx); break;                            \
        case 3:  PROD_SET(P, HL, 3, wx); break;                            \
        case 4:  PROD_SET(P, HL, 4, wx); break;                            \
        default: PROD_SET(P, HL, 5, wx); break;                            \
    }                                                                      \
} while (0)
#define SWITCH_MUL(P, HL, LI, J) do {                                      \
    float wx = wx_##LI##_##J;                                              \
    switch (i0_##LI##_##J) {                                               \
        case 2:  PROD_MUL(P, HL, 2, wx); break;                            \
        case 3:  PROD_MUL(P, HL, 3, wx); break;                            \
        case 4:  PROD_MUL(P, HL, 4, wx); break;                            \
        default: PROD_MUL(P, HL, 5, wx); break;                            \
    }                                                                      \
} while (0)
#define SWITCH_ACC(A, P, HL, LI, J) do {                                   \
    float wx = wx_##LI##_##J;                                              \
    switch (i0_##LI##_##J) {                                               \
        case 2:  ACC_FMA(A, P, HL, 2, wx); break;                          \
        case 3:  ACC_FMA(A, P, HL, 3, wx); break;                          \
        case 4:  ACC_FMA(A, P, HL, 4, wx); break;                          \
        default: ACC_FMA(A, P, HL, 5, wx); break;                          \
    }                                                                      \
} while (0)

#define INIT_J(J) do {                                                     \
    acc[J][0] = 0.0f; acc[J][1] = 0.0f; acc[J][2] = 0.0f; acc[J][3] = 0.0f;\
} while (0)

#define DO_J(J) do {                                                       \
    float prod[WPX];                                                       \
    SWITCH_SET(prod, h0, 0, J);                                            \
    SWITCH_MUL(prod, h1, 1, J);                                            \
    SWITCH_ACC(acc[J], prod, h2, 2, J);                                    \
} while (0)

#define STORE_J(J) do {                                                    \
    float* op = out + obase + (size_t)((J) * CN) * HWSZ;                   \
    *(float4*)(op) = make_float4(acc[J][0] * 0.25f, acc[J][1] * 0.25f,     \
                                 acc[J][2] * 0.25f, acc[J][3] * 0.25f);    \
} while (0)

// per-(l,j) scalar horizontal (wx, i0): uniform per block -> force SGPR
#define PRE_X(L, J)                                                        \
    float wx_##L##_##J; int i0_##L##_##J;                                  \
    do {                                                                   \
        float dx  = p##L * (-(float)((J) - 3) * (0.5f * (float)(WW - 1) / (float)WW)); \
        float oxf = floorf(dx);                                            \
        wx_##L##_##J = __uint_as_float(__builtin_amdgcn_readfirstlane(__float_as_uint(dx - oxf))); \
        i0_##L##_##J = __builtin_amdgcn_readfirstlane((int)oxf + 4);       \
    } while (0)

// per-layer preamble: y-side clamped bilinear row selection (per-thread)
#define PRE_L(L)                                                           \
    float p##L = planes[n * NL + (L)];                                     \
    float wy##L; int off##L;                                               \
    do {                                                                   \
        float Y  = fminf(fmaxf((float)y + p##L * syk, 0.0f), (float)(HH - 1)); \
        float yf = floorf(Y);                                              \
        int y0   = (int)yf;                                                \
        if (y0 > HH - 2) y0 = HH - 2;                                      \
        wy##L    = Y - (float)y0;                                          \
        off##L   = y0 * WW + xb;                                           \
    } while (0);                                                           \
    PRE_X(L, 0); PRE_X(L, 1); PRE_X(L, 2); PRE_X(L, 3);                    \
    PRE_X(L, 4); PRE_X(L, 5); PRE_X(L, 6)

// ---------------- main: 4 px x 7 views, pad fused, one (n,k,c) per group -------
// __launch_bounds__(256, 8): 8 waves/EU -> VGPR cap 64 -> 8-wave occupancy
// bucket (round-7 post-mortem).
__global__ __launch_bounds__(256, 8) void ml12_kernel(const float* __restrict__ low_rank,
                                                      const float* __restrict__ planes,
                                                      float* __restrict__ out)
{
    int bid = (int)blockIdx.x;
    int g   = (bid & 7) * 504 + (bid >> 3);      // bijective: 4032 = 8*504
    int pb  = g % PBN;
    int t   = g / PBN;
    int k   = t % ANGN;
    int nc  = t / ANGN;
    int c   = nc % CN;
    int n   = nc / CN;

    int g4 = pb * 256 + (int)threadIdx.x;        // [0, 24576)
    int xg = g4 % GX;
    int y  = g4 / GX;
    int xb = xg * WPX;                           // first of 4 pixels

    bool eL = (xg == 0);
    bool eR = (xg == GX - 1);
    int dq0 = eL ? 0 : -4;                       // quad 0 col: xb-4 (clamped)
    int dq2 = eR ? 0 : 4;                        // quad 2 col: xb+4 (clamped)

    const float syk = -(float)(k - 3) * (0.5f * (float)(HH - 1) / (float)HH);

    PRE_L(0); PRE_L(1); PRE_L(2);

    float acc[ANGN][WPX];
    INIT_J(0); INIT_J(1); INIT_J(2); INIT_J(3); INIT_J(4); INIT_J(5); INIT_J(6);

#pragma unroll 1
    for (int r = 0; r < RANKN; r++) {
        float h0[10], h1[10], h2[10];            // indices 2..9 valid
        STAGE(h0, 0);
        STAGE(h1, 1);
        STAGE(h2, 2);

        DO_J(0); DO_J(1); DO_J(2); DO_J(3); DO_J(4); DO_J(5); DO_J(6);
    }

    size_t obase = ((size_t)((n * A2N + k * ANGN) * CN + c)) * HWSZ
                 + (size_t)y * WW + xb;
    STORE_J(0); STORE_J(1); STORE_J(2); STORE_J(3);
    STORE_J(4); STORE_J(5); STORE_J(6);
}

extern "C" void kernel_launch(void* const* d_in, const int* in_sizes, int n_in,
                              void* d_out, int out_size, void* d_ws, size_t ws_size,
                              hipStream_t stream) {
    const float* low_rank = (const float*)d_in[0];
    const float* planes   = (const float*)d_in[1];
    float* out = (float*)d_out;

    int ml_blocks = NBATCH * CN * ANGN * PBN;    // 4032
    ml12_kernel<<<ml_blocks, 256, 0, stream>>>(low_rank, planes, out);
}

// Round 10
// 232.717 us; speedup vs baseline: 2.7264x; 2.7264x over previous
//
#include <hip/hip_runtime.h>

#define HH 256
#define WW 384
#define HWSZ (HH*WW)
#define NL 3
#define ANGN 7
#define A2N 49
#define NBATCH 2
#define RANKN 4
#define CN 3
#define RCN (RANKN*CN)

#define WPX 4                       // pixels per thread
#define GX (WW/WPX)                 // 96 pixel-groups per row
#define PBN ((HH*GX)/256)           // 96 pixel-blocks per (n,k,c)
// grid = NBATCH*CN*ANGN*PBN = 2*3*7*96 = 4032 = 8*504 (XCD-bijective)

// NOTE (round-2 post-mortem): every register-array subscript must be a
// compile-time literal — runtime-indexed locals go to scratch (2.5 GB spill).
// NOTE (round-5 post-mortem): no explicit software pipeline — VGPR 176 cut
// occupancy to 10.7% and regressed 92->139 us. TLP > ILP here.
// NOTE (round-7/8 post-mortem): VGPR in (64,128] -> 4-waves/SIMD bucket.
// Forcing a cap via __launch_bounds__(256,8) collapsed to VGPR=32 + 2.3 GB
// scratch (543 us). Shrink state naturally, never cap.
// NOTE (round-9 post-mortem): WPX=2 broke 16B alignment (odd xg -> xb-4 not
// mult of 4) and read col -2 at y0=0 -> core dump. Any footprint change needs
// a fresh alignment + min/max-address proof. WPX=4 geometry is proven safe.
// NOTE (round-10 design): block order k innermost / c / pb / n outermost.
// ml7 (88us) vs ml11 (147us) differ only in ordering+FETCH (16.5 vs 97 MB):
// per-XCD working set must stay < 4 MB L2. Here: 504 consecutive g = 7k*3c*24pb
// at fixed n -> ~36 images x ~38 rows ~ 2.1 MB -> L2-resident.

// lerp over staged window h[2..9]; sample px t of view j uses h[K+t], h[K+t+1]
#define LERP1(HL, I, WX) ((HL)[I] + (WX) * ((HL)[(I)+1] - (HL)[I]))
#define PROD_SET(P, HL, K, WX) do {                           \
    P[0] = LERP1(HL, (K)+0, WX); P[1] = LERP1(HL, (K)+1, WX); \
    P[2] = LERP1(HL, (K)+2, WX); P[3] = LERP1(HL, (K)+3, WX); \
} while (0)
#define PROD_MUL(P, HL, K, WX) do {                           \
    P[0] *= LERP1(HL, (K)+0, WX); P[1] *= LERP1(HL, (K)+1, WX); \
    P[2] *= LERP1(HL, (K)+2, WX); P[3] *= LERP1(HL, (K)+3, WX); \
} while (0)
#define ACC_FMA(A, P, HL, K, WX) do {                         \
    A[0] = fmaf(P[0], LERP1(HL, (K)+0, WX), A[0]);            \
    A[1] = fmaf(P[1], LERP1(HL, (K)+1, WX), A[1]);            \
    A[2] = fmaf(P[2], LERP1(HL, (K)+2, WX), A[2]);            \
    A[3] = fmaf(P[3], LERP1(HL, (K)+3, WX), A[3]);            \
} while (0)

// stage one (layer L, rank r) row-pair directly from UNPADDED input.
// Quads at cols xb-4 (clamped), xb, xb+4 (clamped); border replicate via 4
// selects on the vertical-lerp results. h[i] = value at col xb-4+i, i in 2..9.
#define STAGE(HL, L) do {                                                   \
    const float* cb = low_rank + (size_t)(((n * NL + (L)) * RANKN + r) * CN + c) * HWSZ; \
    const float* p0 = cb + off##L;                                          \
    const float* p1 = p0 + WW;                                              \
    float4 a0 = *(const float4*)(p0 + dq0);                                 \
    float4 a1 = *(const float4*)(p0);                                       \
    float4 a2 = *(const float4*)(p0 + dq2);                                 \
    float4 b0 = *(const float4*)(p1 + dq0);                                 \
    float4 b1 = *(const float4*)(p1);                                       \
    float4 b2 = *(const float4*)(p1 + dq2);                                 \
    float w = wy##L;                                                        \
    float v0x = a0.x + w * (b0.x - a0.x);                                   \
    float v0z = a0.z + w * (b0.z - a0.z);                                   \
    float v0w = a0.w + w * (b0.w - a0.w);                                   \
    HL[2] = eL ? v0x : v0z;                                                 \
    HL[3] = eL ? v0x : v0w;                                                 \
    HL[4] = a1.x + w * (b1.x - a1.x);                                       \
    HL[5] = a1.y + w * (b1.y - a1.y);                                       \
    HL[6] = a1.z + w * (b1.z - a1.z);                                       \
    HL[7] = a1.w + w * (b1.w - a1.w);                                       \
    float v2x = a2.x + w * (b2.x - a2.x);                                   \
    float v2y = a2.y + w * (b2.y - a2.y);                                   \
    float v2w = a2.w + w * (b2.w - a2.w);                                   \
    HL[8] = eR ? v2w : v2x;                                                 \
    HL[9] = eR ? v2w : v2y;                                                 \
} while (0)

#define SWITCH_SET(P, HL, LI, J) do {                                      \
    float wx = wx_##LI##_##J;                                              \
    switch (i0_##LI##_##J) {                                               \
        case 2:  PROD_SET(P, HL, 2, wx); break;                            \
        case 3:  PROD_SET(P, HL, 3, wx); break;                            \
        case 4:  PROD_SET(P, HL, 4, wx); break;                            \
        default: PROD_SET(P, HL, 5, wx); break;                            \
    }                                                                      \
} while (0)
#define SWITCH_MUL(P, HL, LI, J) do {                                      \
    float wx = wx_##LI##_##J;                                              \
    switch (i0_##LI##_##J) {                                               \
        case 2:  PROD_MUL(P, HL, 2, wx); break;                            \
        case 3:  PROD_MUL(P, HL, 3, wx); break;                            \
        case 4:  PROD_MUL(P, HL, 4, wx); break;                            \
        default: PROD_MUL(P, HL, 5, wx); break;                            \
    }                                                                      \
} while (0)
#define SWITCH_ACC(A, P, HL, LI, J) do {                                   \
    float wx = wx_##LI##_##J;                                              \
    switch (i0_##LI##_##J) {                                               \
        case 2:  ACC_FMA(A, P, HL, 2, wx); break;                          \
        case 3:  ACC_FMA(A, P, HL, 3, wx); break;                          \
        case 4:  ACC_FMA(A, P, HL, 4, wx); break;                          \
        default: ACC_FMA(A, P, HL, 5, wx); break;                          \
    }                                                                      \
} while (0)

#define INIT_J(J) do {                                                     \
    acc[J][0] = 0.0f; acc[J][1] = 0.0f; acc[J][2] = 0.0f; acc[J][3] = 0.0f;\
} while (0)

#define DO_J(J) do {                                                       \
    float prod[WPX];                                                       \
    SWITCH_SET(prod, h0, 0, J);                                            \
    SWITCH_MUL(prod, h1, 1, J);                                            \
    SWITCH_ACC(acc[J], prod, h2, 2, J);                                    \
} while (0)

#define STORE_J(J) do {                                                    \
    float* op = out + obase + (size_t)((J) * CN) * HWSZ;                   \
    *(float4*)(op) = make_float4(acc[J][0] * 0.25f, acc[J][1] * 0.25f,     \
                                 acc[J][2] * 0.25f, acc[J][3] * 0.25f);    \
} while (0)

// per-(l,j) scalar horizontal (wx, i0): uniform per block -> force SGPR
#define PRE_X(L, J)                                                        \
    float wx_##L##_##J; int i0_##L##_##J;                                  \
    do {                                                                   \
        float dx  = p##L * (-(float)((J) - 3) * (0.5f * (float)(WW - 1) / (float)WW)); \
        float oxf = floorf(dx);                                            \
        wx_##L##_##J = __uint_as_float(__builtin_amdgcn_readfirstlane(__float_as_uint(dx - oxf))); \
        i0_##L##_##J = __builtin_amdgcn_readfirstlane((int)oxf + 4);       \
    } while (0)

// per-layer preamble: y-side clamped bilinear row selection (per-thread)
#define PRE_L(L)                                                           \
    float p##L = planes[n * NL + (L)];                                     \
    float wy##L; int off##L;                                               \
    do {                                                                   \
        float Y  = fminf(fmaxf((float)y + p##L * syk, 0.0f), (float)(HH - 1)); \
        float yf = floorf(Y);                                              \
        int y0   = (int)yf;                                                \
        if (y0 > HH - 2) y0 = HH - 2;                                      \
        wy##L    = Y - (float)y0;                                          \
        off##L   = y0 * WW + xb;                                           \
    } while (0);                                                           \
    PRE_X(L, 0); PRE_X(L, 1); PRE_X(L, 2); PRE_X(L, 3);                    \
    PRE_X(L, 4); PRE_X(L, 5); PRE_X(L, 6)

// ---------------- main: 4 px x 7 views; k,c innermost, pb middle, n outer ------
__global__ __launch_bounds__(256) void ml14_kernel(const float* __restrict__ low_rank,
                                                   const float* __restrict__ planes,
                                                   float* __restrict__ out)
{
    int bid = (int)blockIdx.x;
    int g   = (bid & 7) * 504 + (bid >> 3);      // bijective: 4032 = 8*504
    int k   = g % ANGN;                          // innermost: 7 views of same rows
    int t   = g / ANGN;
    int c   = t % CN;                            // then 3 channels
    int t2  = t / CN;
    int pb  = t2 % PBN;                          // then pixel-blocks
    int n   = t2 / PBN;                          // batch outermost

    int g4 = pb * 256 + (int)threadIdx.x;        // [0, 24576)
    int xg = g4 % GX;
    int y  = g4 / GX;
    int xb = xg * WPX;                           // first of 4 pixels

    bool eL = (xg == 0);
    bool eR = (xg == GX - 1);
    int dq0 = eL ? 0 : -4;                       // quad 0 col: xb-4 (clamped)
    int dq2 = eR ? 0 : 4;                        // quad 2 col: xb+4 (clamped)

    const float syk = -(float)(k - 3) * (0.5f * (float)(HH - 1) / (float)HH);

    PRE_L(0); PRE_L(1); PRE_L(2);

    float acc[ANGN][WPX];
    INIT_J(0); INIT_J(1); INIT_J(2); INIT_J(3); INIT_J(4); INIT_J(5); INIT_J(6);

#pragma unroll 1
    for (int r = 0; r < RANKN; r++) {
        float h0[10], h1[10], h2[10];            // indices 2..9 valid
        STAGE(h0, 0);
        STAGE(h1, 1);
        STAGE(h2, 2);

        DO_J(0); DO_J(1); DO_J(2); DO_J(3); DO_J(4); DO_J(5); DO_J(6);
    }

    size_t obase = ((size_t)((n * A2N + k * ANGN) * CN + c)) * HWSZ
                 + (size_t)y * WW + xb;
    STORE_J(0); STORE_J(1); STORE_J(2); STORE_J(3);
    STORE_J(4); STORE_J(5); STORE_J(6);
}

extern "C" void kernel_launch(void* const* d_in, const int* in_sizes, int n_in,
                              void* d_out, int out_size, void* d_ws, size_t ws_size,
                              hipStream_t stream) {
    const float* low_rank = (const float*)d_in[0];
    const float* planes   = (const float*)d_in[1];
    float* out = (float*)d_out;

    int ml_blocks = NBATCH * CN * ANGN * PBN;    // 4032
    ml14_kernel<<<ml_blocks, 256, 0, stream>>>(low_rank, planes, out);
}